// Round 1
// baseline (2770.601 us; speedup 1.0000x reference)
//
#include <hip/hip_runtime.h>
#include <math.h>

#define HID 128
#define NRBF 50
#define NRBF_PAD 52
#define CUTOFF_F 10.0f

// fast tanh via exp2-based __expf; clamp avoids inf/inf NaN. rel err ~1e-6.
__device__ __forceinline__ float tanh_fast(float x) {
    float xc = fminf(fmaxf(x, -15.0f), 15.0f);
    float e = __expf(2.0f * xc);
    return (e - 1.0f) / (e + 1.0f);
}

// ---------------- kernel 1: xt = x @ w_lin1^T  [N,128] ----------------
// LDS: w in pair-of-k interleave: wq[k2][4*l + 2*kk + sel] = w[(l+64*sel)*128 + 2*k2+kk]
__global__ __launch_bounds__(512) void k_lin1(const float* __restrict__ x,
                                              const float* __restrict__ w1,
                                              float* __restrict__ xt, int nrows) {
    __shared__ float wq[64][256];   // 64 KiB
    __shared__ float xs[64][128];   // 32 KiB
    int tid = threadIdx.x;
    for (int idx = tid; idx < 128 * 128; idx += 512) {
        int h = idx >> 7, k = idx & 127;
        int l = h & 63, sel = h >> 6, k2 = k >> 1, kk = k & 1;
        wq[k2][4 * l + 2 * kk + sel] = w1[idx];
    }
    __syncthreads();
    int wid = tid >> 6, lane = tid & 63;
    for (int base = blockIdx.x * 64; base < nrows; base += gridDim.x * 64) {
        int navail = min(64, nrows - base);
        __syncthreads();
        for (int i = tid; i < navail * 128; i += 512)
            xs[0][i] = x[(size_t)base * 128 + i];
        __syncthreads();
        int r0 = wid * 8;
        float acc[8][2];
#pragma unroll
        for (int e = 0; e < 8; e++) { acc[e][0] = 0.0f; acc[e][1] = 0.0f; }
        for (int k4 = 0; k4 < 32; k4++) {
            float4 wa = *(const float4*)&wq[2 * k4][4 * lane];
            float4 wb = *(const float4*)&wq[2 * k4 + 1][4 * lane];
#pragma unroll
            for (int e = 0; e < 8; e++) {
                float4 xv = *(const float4*)&xs[r0 + e][4 * k4];
                acc[e][0] += xv.x * wa.x + xv.y * wa.z + xv.z * wb.x + xv.w * wb.z;
                acc[e][1] += xv.x * wa.y + xv.y * wa.w + xv.z * wb.y + xv.w * wb.w;
            }
        }
#pragma unroll
        for (int e = 0; e < 8; e++) {
            int r = base + r0 + e;
            if (r < nrows) {
                xt[(size_t)r * 128 + lane] = acc[e][0];
                xt[(size_t)r * 128 + lane + 64] = acc[e][1];
            }
        }
    }
}

// ---------------- kernel 2: per-edge filter MLP + envelope + gather + scatter ----------------
__global__ __launch_bounds__(512) void k_edge(
    const float* __restrict__ edge_attr, const int* __restrict__ ei,
    const float* __restrict__ ew, const float* __restrict__ fw1,
    const float* __restrict__ fb1, const float* __restrict__ fw2,
    const float* __restrict__ fb2, const float* __restrict__ xt,
    float* __restrict__ agg, int nedges) {
    __shared__ float w1q[26][256];          // 26 KiB (k padded 50->52, zeros)
    __shared__ float w2q[64][256];          // 64 KiB
    __shared__ float attr_s[64][NRBF_PAD];  // 13 KiB (row stride 208B = 13*16 ok for float4)
    __shared__ float t_s[64][128];          // 32 KiB
    int tid = threadIdx.x;
    for (int idx = tid; idx < 26 * 256; idx += 512) {
        int k2 = idx >> 8, j = idx & 255;
        int l = j >> 2, q = j & 3, kk = q >> 1, sel = q & 1;
        int k = 2 * k2 + kk, h = l + (sel << 6);
        w1q[k2][j] = (k < NRBF) ? fw1[k * HID + h] : 0.0f;
    }
    for (int idx = tid; idx < 64 * 256; idx += 512) {
        int k2 = idx >> 8, j = idx & 255;
        int l = j >> 2, q = j & 3, kk = q >> 1, sel = q & 1;
        int k = 2 * k2 + kk, h = l + (sel << 6);
        w2q[k2][j] = fw2[k * HID + h];
    }
    int wid = tid >> 6, lane = tid & 63;
    float b1a = fb1[lane], b1b = fb1[lane + 64];
    float b2a = fb2[lane], b2b = fb2[lane + 64];
    __syncthreads();

    const float k_pi = 3.14159265358979f / CUTOFF_F;
    for (int ebase = blockIdx.x * 64; ebase < nedges; ebase += gridDim.x * 64) {
        int navail = min(64, nedges - ebase);
        __syncthreads();
        for (int i = tid; i < navail * NRBF; i += 512) {
            int e = i / NRBF, k = i - e * NRBF;
            attr_s[e][k] = edge_attr[(size_t)ebase * NRBF + i];
        }
        for (int i = tid; i < 64 * 2; i += 512) attr_s[i >> 1][NRBF + (i & 1)] = 0.0f;
        __syncthreads();

        int e0 = wid * 8;
        float acc[8][2];
#pragma unroll
        for (int e = 0; e < 8; e++) { acc[e][0] = b1a; acc[e][1] = b1b; }
        for (int k4 = 0; k4 < 13; k4++) {
            float4 wa = *(const float4*)&w1q[2 * k4][4 * lane];
            float4 wb = *(const float4*)&w1q[2 * k4 + 1][4 * lane];
#pragma unroll
            for (int e = 0; e < 8; e++) {
                float4 av = *(const float4*)&attr_s[e0 + e][4 * k4];
                acc[e][0] += av.x * wa.x + av.y * wa.z + av.z * wb.x + av.w * wb.z;
                acc[e][1] += av.x * wa.y + av.y * wa.w + av.z * wb.y + av.w * wb.w;
            }
        }
        // tanh -> t_s (wave-private rows; per-wave LDS in-order, no barrier needed)
#pragma unroll
        for (int e = 0; e < 8; e++) {
            t_s[e0 + e][lane] = tanh_fast(acc[e][0]);
            t_s[e0 + e][lane + 64] = tanh_fast(acc[e][1]);
        }
        float acc2[8][2];
#pragma unroll
        for (int e = 0; e < 8; e++) { acc2[e][0] = b2a; acc2[e][1] = b2b; }
        for (int k4 = 0; k4 < 32; k4++) {
            float4 wa = *(const float4*)&w2q[2 * k4][4 * lane];
            float4 wb = *(const float4*)&w2q[2 * k4 + 1][4 * lane];
#pragma unroll
            for (int e = 0; e < 8; e++) {
                float4 tv = *(const float4*)&t_s[e0 + e][4 * k4];
                acc2[e][0] += tv.x * wa.x + tv.y * wa.z + tv.z * wb.x + tv.w * wb.z;
                acc2[e][1] += tv.x * wa.y + tv.y * wa.w + tv.z * wb.y + tv.w * wb.w;
            }
        }
#pragma unroll
        for (int e = 0; e < 8; e++) {
            int eid = ebase + e0 + e;
            if (eid < nedges) {
                int s = ei[eid], d = ei[nedges + eid];
                float w = ew[eid];
                float c = (w < CUTOFF_F) ? 0.5f * (__cosf(w * k_pi) + 1.0f) : 0.0f;
                float m0 = xt[(size_t)s * HID + lane] * acc2[e][0] * c;
                float m1 = xt[(size_t)s * HID + lane + 64] * acc2[e][1] * c;
                unsafeAtomicAdd(&agg[(size_t)d * HID + lane], m0);
                unsafeAtomicAdd(&agg[(size_t)d * HID + lane + 64], m1);
            }
        }
    }
}

// ---------------- kernel 3: out = tanh(agg @ w_lin2^T + b2) @ w_out^T + bo (in place on d_out) ----------------
__global__ __launch_bounds__(512) void k_out(const float* __restrict__ w2,
                                             const float* __restrict__ b2,
                                             const float* __restrict__ wo,
                                             const float* __restrict__ bo,
                                             float* __restrict__ io, int nrows) {
    __shared__ float w2q[64][256];  // 64 KiB
    __shared__ float woq[64][256];  // 64 KiB
    __shared__ float rs[32][128];   // 16 KiB (agg rows, reused for tanh(h))
    int tid = threadIdx.x;
    for (int idx = tid; idx < 128 * 128; idx += 512) {
        int h = idx >> 7, k = idx & 127;
        int l = h & 63, sel = h >> 6, k2 = k >> 1, kk = k & 1;
        int j = 4 * l + 2 * kk + sel;
        w2q[k2][j] = w2[idx];
        woq[k2][j] = wo[idx];
    }
    int wid = tid >> 6, lane = tid & 63;
    float ba = b2[lane], bb = b2[lane + 64];
    float ca = bo[lane], cb = bo[lane + 64];
    __syncthreads();
    for (int base = blockIdx.x * 32; base < nrows; base += gridDim.x * 32) {
        int navail = min(32, nrows - base);
        __syncthreads();
        for (int i = tid; i < navail * 128; i += 512)
            rs[0][i] = io[(size_t)base * 128 + i];
        __syncthreads();
        int r0 = wid * 4;
        float acc[4][2];
#pragma unroll
        for (int e = 0; e < 4; e++) { acc[e][0] = ba; acc[e][1] = bb; }
        for (int k4 = 0; k4 < 32; k4++) {
            float4 wa = *(const float4*)&w2q[2 * k4][4 * lane];
            float4 wb = *(const float4*)&w2q[2 * k4 + 1][4 * lane];
#pragma unroll
            for (int e = 0; e < 4; e++) {
                float4 xv = *(const float4*)&rs[r0 + e][4 * k4];
                acc[e][0] += xv.x * wa.x + xv.y * wa.z + xv.z * wb.x + xv.w * wb.z;
                acc[e][1] += xv.x * wa.y + xv.y * wa.w + xv.z * wb.y + xv.w * wb.w;
            }
        }
        // tanh back into own rows (wave-private; per-wave LDS ordering suffices)
#pragma unroll
        for (int e = 0; e < 4; e++) {
            rs[r0 + e][lane] = tanh_fast(acc[e][0]);
            rs[r0 + e][lane + 64] = tanh_fast(acc[e][1]);
        }
        float acc2[4][2];
#pragma unroll
        for (int e = 0; e < 4; e++) { acc2[e][0] = ca; acc2[e][1] = cb; }
        for (int k4 = 0; k4 < 32; k4++) {
            float4 wa = *(const float4*)&woq[2 * k4][4 * lane];
            float4 wb = *(const float4*)&woq[2 * k4 + 1][4 * lane];
#pragma unroll
            for (int e = 0; e < 4; e++) {
                float4 tv = *(const float4*)&rs[r0 + e][4 * k4];
                acc2[e][0] += tv.x * wa.x + tv.y * wa.z + tv.z * wb.x + tv.w * wb.z;
                acc2[e][1] += tv.x * wa.y + tv.y * wa.w + tv.z * wb.y + tv.w * wb.w;
            }
        }
#pragma unroll
        for (int e = 0; e < 4; e++) {
            int r = base + r0 + e;
            if (r < nrows) {
                io[(size_t)r * 128 + lane] = acc2[e][0];
                io[(size_t)r * 128 + lane + 64] = acc2[e][1];
            }
        }
    }
}

extern "C" void kernel_launch(void* const* d_in, const int* in_sizes, int n_in,
                              void* d_out, int out_size, void* d_ws, size_t ws_size,
                              hipStream_t stream) {
    const float* x   = (const float*)d_in[0];
    const int*   ei  = (const int*)d_in[1];
    const float* ew  = (const float*)d_in[2];
    const float* ea  = (const float*)d_in[3];
    const float* fw1 = (const float*)d_in[4];
    const float* fb1 = (const float*)d_in[5];
    const float* fw2 = (const float*)d_in[6];
    const float* fb2 = (const float*)d_in[7];
    const float* wl1 = (const float*)d_in[8];
    const float* wl2 = (const float*)d_in[9];
    const float* bl2 = (const float*)d_in[10];
    const float* wo  = (const float*)d_in[11];
    const float* bo  = (const float*)d_in[12];

    int nnodes = in_sizes[0] / HID;   // 100000
    int nedges = in_sizes[2];         // 1600000 (edge_weight count)
    float* out = (float*)d_out;
    float* xt  = (float*)d_ws;        // [nnodes][128] f32 = 51.2 MB

    hipMemsetAsync(d_out, 0, (size_t)out_size * sizeof(float), stream);
    k_lin1<<<512, 512, 0, stream>>>(x, wl1, xt, nnodes);
    k_edge<<<256, 512, 0, stream>>>(ea, ei, ew, fw1, fb1, fw2, fb2, xt, out, nedges);
    k_out<<<256, 512, 0, stream>>>(wl2, bl2, wo, bo, out, nnodes);
}